// Round 14
// baseline (2623.581 us; speedup 1.0000x reference)
//
#include <hip/hip_runtime.h>

typedef unsigned char u8;
typedef unsigned int u32;

#define T_STEPS 4
#define B_SZ 8
#define C_IN 512
#define CH 2048
#define N_SP 1024
#define S_C ((size_t)B_SZ * C_IN * N_SP)    // elems per timestep

// ---------------------------------------------------------------------------
// lif_x: x [T,B,C,N] fp32 -> xs u8 spikes, same flat layout (round-2 verbatim).
// ---------------------------------------------------------------------------
__global__ __launch_bounds__(256) void lif_x_kernel(const float* __restrict__ in,
                                                    u8* __restrict__ out)
{
    size_t i = (size_t)blockIdx.x * 256 + threadIdx.x;
    float v = 0.0f;
    #pragma unroll
    for (int t = 0; t < T_STEPS; ++t) {
        float x = in[(size_t)t * S_C + i];
        v += (x - v) * 0.5f;
        u8 s = (v >= 0.5f) ? 1 : 0;
        out[(size_t)t * S_C + i] = s;
        v = s ? 0.0f : v;
    }
}

// ---------------------------------------------------------------------------
// Fused GEMM + BN (+bias) + LIF, fp32, T-FOLDED (round 13) + round 14:
//   - NW template = waves per block (2 or 4). NW=2: 32co x 64n x 4t tile,
//     128 threads -> 8 blocks/CU at same 16 waves/CU; barrier scope halved
//     and twice as many independent blocks overlap the barrier drains.
//     NW=4: round-13 shape (fc1 keeps it: fp32 prefetch needs 32 regs and
//     NW=2 would risk the >128-VGPR occupancy cliff of round 11).
//   - Grid order: cb fastest (XCD x keeps only W slices == x mod 8 ->
//     ~512KB L2-resident), then nblk, then b slowest -> X chunks stay hot.
// Per output element: ascending-k, single fp32 accumulator; epilogue
// expressions identical to rounds 2/6/9/13 -> bit-identical output.
// Layouts: X [TB][K][N], W [CO][K] fp32, Y [TB][CO][N].
// MODE 0: LIF -> u8 spikes. MODE 1: y + res -> f32. MODE 2: LIF spike + in-place res -> f32.
// BSRC 0: u8 X. BSRC 1: u8 X * kvsf[t][k] at staging (proj mask). BSRC 2: f32 X (fc1).
// NOTE: no min-waves hint (round 8: (256,4) clamps to 64 VGPR and spills).
// ---------------------------------------------------------------------------
template<int NW, int MODE, int BSRC, bool BIAS, int K, int CO, int NSEL>
__global__ __launch_bounds__(NW * 64) void mm(
    const float* __restrict__ W0, const float* __restrict__ W1, const float* __restrict__ W2,
    const void* __restrict__ Xv,
    const float* __restrict__ bn0, const float* __restrict__ bn1, const float* __restrict__ bn2,
    const float* __restrict__ bias,
    const float* __restrict__ kvsf,
    const float* __restrict__ res,
    void* Y0, void* Y1, void* Y2)
{
    constexpr int BM = NW * 16;          // co rows per block
    constexpr int NB_CB = CO / BM;
    constexpr int CBTOT = NB_CB * NSEL;  // multiple of 8 in all instantiations
    constexpr int KT = K / 16;
    constexpr int TYN = NW * 4;          // distinct ty values
    constexpr int HX = 16 / TYN;         // X row-groups per thread (1 or 2)

    __shared__ float As[16][BM + 4];     // [k][co]
    __shared__ float Xs[4][16][68];      // [t][k][n]

    const int bid = blockIdx.x;
    const int cbsel = bid % CBTOT;       // fastest: W slice per XCD stays resident
    const int rr = bid / CBTOT;
    const int nblk = rr % 16;
    const int b = rr / 16;
    const int cb = (NSEL > 1) ? (cbsel % NB_CB) : cbsel;
    const int sel = (NSEL > 1) ? (cbsel / NB_CB) : 0;

    const float* W   = (NSEL == 1 || sel == 0) ? W0  : (sel == 1 ? W1  : W2);
    const float* bnp = (NSEL == 1 || sel == 0) ? bn0 : (sel == 1 ? bn1 : bn2);
    void* Yv         = (NSEL == 1 || sel == 0) ? Y0  : (sel == 1 ? Y1  : Y2);

    const int coBase = cb * BM;
    const int n0blk = nblk * 64;
    const int tid = threadIdx.x;
    const int tx = tid & 15, ty = tid >> 4;   // ty in [0, TYN)

    // staging indices: W row = tid>>2 in [0,BM), 4 k each; X rows ty + TYN*h
    const int wr = tid >> 2;
    const int wk4 = (tid & 3) * 4;

    // BN constants (round-2 expressions)
    float scale[4], shift[4];
    #pragma unroll
    for (int i = 0; i < 4; ++i) {
        const int co = coBase + ty * 4 + i;
        const float g = bnp[co], be = bnp[CO + co];
        const float mn = bnp[2 * CO + co], vr = bnp[3 * CO + co];
        scale[i] = g / sqrtf(vr + 1e-5f);
        shift[i] = be - mn * scale[i];
        if (BIAS) shift[i] += bias[co] * scale[i];
    }

    float acc[4][4][4];   // [t][co i][n j]
    #pragma unroll
    for (int t = 0; t < 4; ++t)
        #pragma unroll
        for (int i = 0; i < 4; ++i)
            #pragma unroll
            for (int j = 0; j < 4; ++j) acc[t][i][j] = 0.0f;

    float4 wreg;
    u32 xu[4][HX];
    float mreg[4][HX];
    float4 xf[4][HX];

    auto prefetch = [&](int kt) {
        wreg = *reinterpret_cast<const float4*>(
            W + (size_t)(coBase + wr) * K + kt * 16 + wk4);
        #pragma unroll
        for (int t = 0; t < 4; ++t) {
            const int tb = t * B_SZ + b;
            #pragma unroll
            for (int h = 0; h < HX; ++h) {
                const int row = kt * 16 + ty + TYN * h;
                if constexpr (BSRC <= 1) {
                    xu[t][h] = *reinterpret_cast<const u32*>(
                        (const u8*)Xv + (size_t)tb * K * N_SP
                        + (size_t)row * N_SP + n0blk + tx * 4);
                    if constexpr (BSRC == 1)
                        mreg[t][h] = kvsf[(size_t)tb * K + row];
                } else {
                    xf[t][h] = *reinterpret_cast<const float4*>(
                        (const float*)Xv + (size_t)tb * K * N_SP
                        + (size_t)row * N_SP + n0blk + tx * 4);
                }
            }
        }
    };

    prefetch(0);

    for (int kt = 0; kt < KT; ++kt) {
        __syncthreads();    // previous tile's compute done; LDS reusable
        As[wk4 + 0][wr] = wreg.x;
        As[wk4 + 1][wr] = wreg.y;
        As[wk4 + 2][wr] = wreg.z;
        As[wk4 + 3][wr] = wreg.w;
        #pragma unroll
        for (int t = 0; t < 4; ++t) {
            #pragma unroll
            for (int h = 0; h < HX; ++h) {
                float4 s0;
                if constexpr (BSRC <= 1) {
                    s0.x = (float)( xu[t][h]        & 0xFFu);
                    s0.y = (float)((xu[t][h] >> 8 ) & 0xFFu);
                    s0.z = (float)((xu[t][h] >> 16) & 0xFFu);
                    s0.w = (float)( xu[t][h] >> 24        );
                    if constexpr (BSRC == 1) {
                        s0.x *= mreg[t][h]; s0.y *= mreg[t][h];   // 0/1 x 0/1: exact
                        s0.z *= mreg[t][h]; s0.w *= mreg[t][h];
                    }
                } else {
                    s0 = xf[t][h];
                }
                *reinterpret_cast<float4*>(&Xs[t][ty + TYN * h][tx * 4]) = s0;
            }
        }
        __syncthreads();
        if (kt + 1 < KT) prefetch(kt + 1);   // overlaps with compute below

        #pragma unroll
        for (int kk = 0; kk < 16; ++kk) {
            float4 av = *reinterpret_cast<const float4*>(&As[kk][ty * 4]);
            float wa[4] = {av.x, av.y, av.z, av.w};
            #pragma unroll
            for (int t = 0; t < 4; ++t) {
                float4 xv = *reinterpret_cast<const float4*>(&Xs[t][kk][tx * 4]);
                float xw[4] = {xv.x, xv.y, xv.z, xv.w};
                #pragma unroll
                for (int i = 0; i < 4; ++i)
                    #pragma unroll
                    for (int j = 0; j < 4; ++j)
                        acc[t][i][j] += wa[i] * xw[j];   // ascending-k, single acc
            }
        }
    }

    // epilogue: LIF chain over t (ascending), expressions identical to round 2.
    #pragma unroll
    for (int i = 0; i < 4; ++i) {
        const int co = coBase + ty * 4 + i;
        float v[4] = {0.0f, 0.0f, 0.0f, 0.0f};
        #pragma unroll
        for (int t = 0; t < 4; ++t) {
            const int tb = t * B_SZ + b;
            const size_t off = ((size_t)tb * CO + co) * N_SP + n0blk + tx * 4;
            if constexpr (MODE == 0) {
                u32 pk = 0;
                #pragma unroll
                for (int e = 0; e < 4; ++e) {
                    const float y = acc[t][i][e] * scale[i] + shift[i];
                    v[e] += (y - v[e]) * 0.5f;
                    const u32 s = (v[e] >= 0.5f) ? 1u : 0u;
                    v[e] = s ? 0.0f : v[e];
                    pk |= s << (8 * e);
                }
                *reinterpret_cast<u32*>((u8*)Yv + off) = pk;
            } else if constexpr (MODE == 1) {
                float4 r0 = *reinterpret_cast<const float4*>(res + off);
                float rr2[4] = {r0.x, r0.y, r0.z, r0.w};
                float o[4];
                #pragma unroll
                for (int e = 0; e < 4; ++e)
                    o[e] = acc[t][i][e] * scale[i] + shift[i] + rr2[e];
                float4 s0 = {o[0], o[1], o[2], o[3]};
                *reinterpret_cast<float4*>((float*)Yv + off) = s0;
            } else {
                float* op = (float*)Yv + off;
                float4 r0 = *reinterpret_cast<const float4*>(op);
                float rr2[4] = {r0.x, r0.y, r0.z, r0.w};
                float o[4];
                #pragma unroll
                for (int e = 0; e < 4; ++e) {
                    const float y = acc[t][i][e] * scale[i] + shift[i];
                    v[e] += (y - v[e]) * 0.5f;
                    const u32 s = (v[e] >= 0.5f) ? 1u : 0u;
                    v[e] = s ? 0.0f : v[e];
                    o[e] = rr2[e] + (s ? 1.0f : 0.0f);
                }
                float4 s0 = {o[0], o[1], o[2], o[3]};
                *reinterpret_cast<float4*>(op) = s0;
            }
        }
    }
}

// ---------------------------------------------------------------------------
// kv_raw[row=tb*C+c] = sum_n k*v  (exact integer; round-2 verbatim)
// ---------------------------------------------------------------------------
__global__ __launch_bounds__(256) void kv_reduce(const u8* __restrict__ ks,
                                                 const u8* __restrict__ vs,
                                                 float* __restrict__ kv)
{
    const int row = blockIdx.x * 4 + (threadIdx.x >> 6);  // [0, T*B*C)
    const int lane = threadIdx.x & 63;
    const u8* kp = ks + (size_t)row * N_SP;
    const u8* vp = vs + (size_t)row * N_SP;
    int acc = 0;
    #pragma unroll
    for (int n = 0; n < N_SP; n += 256) {
        uchar4 a = *reinterpret_cast<const uchar4*>(kp + n + lane * 4);
        uchar4 c = *reinterpret_cast<const uchar4*>(vp + n + lane * 4);
        acc += (a.x & c.x) + (a.y & c.y) + (a.z & c.z) + (a.w & c.w);
    }
    #pragma unroll
    for (int off = 32; off; off >>= 1) acc += __shfl_down(acc, off, 64);
    if (lane == 0) kv[row] = (float)acc;
}

// ---------------------------------------------------------------------------
// talking heads (8x8 over heads) + LIF -> kvs float {0,1}  (round-2 verbatim)
// ---------------------------------------------------------------------------
__global__ __launch_bounds__(256) void th_lif(const float* __restrict__ kvraw,
                                              const float* __restrict__ th,
                                              float* __restrict__ kvs)
{
    const int i = blockIdx.x * 256 + threadIdx.x;   // [0, B*C)
    const int b = i >> 9;
    const int c = i & 511;
    const int g = c >> 6;
    const int dd = c & 63;
    float v = 0.0f;
    #pragma unroll
    for (int t = 0; t < T_STEPS; ++t) {
        const float* base = kvraw + ((size_t)t * B_SZ + b) * C_IN;
        float x = 0.0f;
        #pragma unroll
        for (int hh = 0; hh < 8; ++hh)
            x += base[hh * 64 + dd] * th[g * 8 + hh];
        v += (x - v) * 0.5f;
        const float s = (v >= 0.5f) ? 1.0f : 0.0f;
        kvs[((size_t)t * B_SZ + b) * C_IN + c] = s;
        v = (s != 0.0f) ? 0.0f : v;
    }
}

extern "C" void kernel_launch(void* const* d_in, const int* in_sizes, int n_in,
                              void* d_out, int out_size, void* d_ws, size_t ws_size,
                              hipStream_t stream)
{
    const float* x       = (const float*)d_in[0];
    const float* q_w     = (const float*)d_in[1];
    const float* q_bn    = (const float*)d_in[2];
    const float* k_w     = (const float*)d_in[3];
    const float* k_bn    = (const float*)d_in[4];
    const float* v_w     = (const float*)d_in[5];
    const float* v_bn    = (const float*)d_in[6];
    const float* th_w    = (const float*)d_in[7];
    const float* proj_w  = (const float*)d_in[8];
    const float* proj_b  = (const float*)d_in[9];
    const float* proj_bn = (const float*)d_in[10];
    const float* fc1_w   = (const float*)d_in[11];
    const float* fc1_b   = (const float*)d_in[12];
    const float* fc1_bn  = (const float*)d_in[13];
    const float* fc2_w   = (const float*)d_in[14];
    const float* fc2_b   = (const float*)d_in[15];
    const float* fc2_bn  = (const float*)d_in[16];
    float* out = (float*)d_out;

    // workspace: round-2/6/9/13's proven 64 MiB + 128 KiB map
    u8* ws = (u8*)d_ws;
    const size_t SLOT = (size_t)T_STEPS * S_C;        // 16 MiB per u8 slot
    u8* xs = ws;                    // [TB][C][N] u8
    u8* qs = ws + SLOT;
    u8* ks = ws + 2 * SLOT;
    u8* vs = ws + 3 * SLOT;
    float* kvraw = (float*)(ws + 4 * SLOT);                 // [TB][C] f32 (64 KiB)
    float* kvsf  = kvraw + (size_t)T_STEPS * B_SZ * C_IN;   // [TB][C] f32 (64 KiB)
    u8* hdn = ws;                   // [TB][Ch][N] u8 = 64 MiB, reuses xs..vs (dead by fc1)

    // 1. xs = lif(x)
    lif_x_kernel<<<(int)(S_C / 256), 256, 0, stream>>>(x, xs);

    // 2. q/k/v = lif(bn(conv(xs)))  — fused triple GEMM, t-folded, NW=2
    //    grid = CBTOT(48) * 16 nblk * 8 b = 6144 blocks of 128 threads
    mm<2, 0, 0, false, 512, 512, 3><<<6144, 128, 0, stream>>>(
        q_w, k_w, v_w, xs, q_bn, k_bn, v_bn, nullptr, nullptr, nullptr, qs, ks, vs);

    // 3. kv_raw = rowwise dot(k, v); 4. talking heads + lif -> kvs (float 0/1)
    kv_reduce<<<(T_STEPS * B_SZ * C_IN) / 4, 256, 0, stream>>>(ks, vs, kvraw);
    th_lif<<<(B_SZ * C_IN) / 256, 256, 0, stream>>>(kvraw, th_w, kvsf);

    // 5. xout = bn(proj(q * kvs) + b) + x  -> d_out; NW=2, grid 16*16*8 = 2048
    mm<2, 1, 1, true, 512, 512, 1><<<2048, 128, 0, stream>>>(
        proj_w, nullptr, nullptr, qs, proj_bn, nullptr, nullptr, proj_b, kvsf, x,
        out, nullptr, nullptr);

    // 6. hdn = lif(bn(fc1(xout) + b)); NW=4 (fp32 prefetch: VGPR safety),
    //    grid = 32 cb * 16 nblk * 8 b = 4096 blocks of 256 threads
    mm<4, 0, 2, true, 512, 2048, 1><<<4096, 256, 0, stream>>>(
        fc1_w, nullptr, nullptr, out, fc1_bn, nullptr, nullptr, fc1_b, nullptr, nullptr,
        hdn, nullptr, nullptr);

    // 7. out = lif(bn(fc2(hdn) + b)) + xout  (in place); NW=2, grid 2048
    mm<2, 2, 0, true, 2048, 512, 1><<<2048, 128, 0, stream>>>(
        fc2_w, nullptr, nullptr, hdn, fc2_bn, nullptr, nullptr, fc2_b, nullptr, nullptr,
        out, nullptr, nullptr);
}

// Round 15
// 2494.453 us; speedup vs baseline: 1.0518x; 1.0518x over previous
//
#include <hip/hip_runtime.h>

typedef unsigned char u8;
typedef unsigned short u16;
typedef unsigned int u32;

#define T_STEPS 4
#define B_SZ 8
#define C_IN 512
#define CH 2048
#define N_SP 1024
#define S_C ((size_t)B_SZ * C_IN * N_SP)    // elems per timestep

// ---------------------------------------------------------------------------
// lif_x: x [T,B,C,N] fp32 -> xs u8 spikes, same flat layout (round-2 verbatim).
// ---------------------------------------------------------------------------
__global__ __launch_bounds__(256) void lif_x_kernel(const float* __restrict__ in,
                                                    u8* __restrict__ out)
{
    size_t i = (size_t)blockIdx.x * 256 + threadIdx.x;
    float v = 0.0f;
    #pragma unroll
    for (int t = 0; t < T_STEPS; ++t) {
        float x = in[(size_t)t * S_C + i];
        v += (x - v) * 0.5f;
        u8 s = (v >= 0.5f) ? 1 : 0;
        out[(size_t)t * S_C + i] = s;
        v = s ? 0.0f : v;
    }
}

// ---------------------------------------------------------------------------
// Fused GEMM + BN (+bias) + LIF, fp32, T-FOLDED (round 13) + round 15 tile:
//   Block tile 128co x 32n x 4t, 256 threads, per-thread 8co x 2n x 4t.
//   Rationale (round 14 lesson: X-staging amortizes over BM -> BM up):
//     - bytes/FMA = A/(j*t) + X/i = 1.0 (was 1.25 at 4co x 4n x 4t)
//     - BM 64->128 halves global X loads + LDS X writes per output element
//     - W staged once per k-tile (t-fold); LIF chain in epilogue (no vst)
//   Staging: W rows by tid>>1 (8 k each); X: wave w stages t=w quadrant.
// Per output element: ascending-k, single fp32 accumulator; epilogue
// expressions identical to rounds 2/6/9/13 -> bit-identical output.
// Layouts: X [TB][K][N], W [CO][K] fp32, Y [TB][CO][N].
// MODE 0: LIF -> u8 spikes. MODE 1: y + res -> f32. MODE 2: LIF spike + in-place res -> f32.
// BSRC 0: u8 X. BSRC 1: u8 X * kvsf[t][k] at staging (proj mask). BSRC 2: f32 X (fc1).
// Grid order: (cb,sel) fastest, then nblk, then b (L2: X slice shared by
// consecutive blocks; W slices cycle while L2/L3-resident).
// NOTE: no min-waves hint (round 8: (256,4) clamps to 64 VGPR and spills).
// ---------------------------------------------------------------------------
template<int MODE, int BSRC, bool BIAS, int K, int CO, int NSEL>
__global__ __launch_bounds__(256) void mm(
    const float* __restrict__ W0, const float* __restrict__ W1, const float* __restrict__ W2,
    const void* __restrict__ Xv,
    const float* __restrict__ bn0, const float* __restrict__ bn1, const float* __restrict__ bn2,
    const float* __restrict__ bias,
    const float* __restrict__ kvsf,
    const float* __restrict__ res,
    void* Y0, void* Y1, void* Y2)
{
    constexpr int NB_CB = CO / 128;
    constexpr int CBTOT = NB_CB * NSEL;
    constexpr int KT = K / 16;

    __shared__ float As[16][132];     // [k][co 128 + pad]
    __shared__ float Xs[4][16][36];   // [t][k][n 32 + pad]  (2-way max, free)

    const int bid = blockIdx.x;
    const int cbsel = bid % CBTOT;    // fastest: consecutive blocks share X slice
    const int rr = bid / CBTOT;
    const int nblk = rr & 31;         // 32 n-slices of 32
    const int b = rr >> 5;
    const int cb = (NSEL > 1) ? (cbsel % NB_CB) : cbsel;
    const int sel = (NSEL > 1) ? (cbsel / NB_CB) : 0;

    const float* W   = (NSEL == 1 || sel == 0) ? W0  : (sel == 1 ? W1  : W2);
    const float* bnp = (NSEL == 1 || sel == 0) ? bn0 : (sel == 1 ? bn1 : bn2);
    void* Yv         = (NSEL == 1 || sel == 0) ? Y0  : (sel == 1 ? Y1  : Y2);

    const int coBase = cb * 128;
    const int n0blk = nblk * 32;
    const int tid = threadIdx.x;
    const int tx = tid & 15;          // n pair index
    const int ty = tid >> 4;          // co group (0..15), 8 co each

    // W staging: row = tid>>1 (128 rows), k-seg = (tid&1)*8
    const int wr = tid >> 1;
    const int wk8 = (tid & 1) * 8;
    // X staging: wave wv stages t=wv; lane -> (k row, n seg)
    const int wv = tid >> 6;
    const int lane = tid & 63;
    const int xrow = lane >> 2;       // 0..15
    const int xn0 = (lane & 3) * 8;   // 0,8,16,24

    // BN constants (round-2 expressions)
    float scale[8], shift[8];
    #pragma unroll
    for (int i = 0; i < 8; ++i) {
        const int co = coBase + ty * 8 + i;
        const float g = bnp[co], be = bnp[CO + co];
        const float mn = bnp[2 * CO + co], vr = bnp[3 * CO + co];
        scale[i] = g / sqrtf(vr + 1e-5f);
        shift[i] = be - mn * scale[i];
        if (BIAS) shift[i] += bias[co] * scale[i];
    }

    float acc[4][8][2];   // [t][co i][n j]
    #pragma unroll
    for (int t = 0; t < 4; ++t)
        #pragma unroll
        for (int i = 0; i < 8; ++i)
            #pragma unroll
            for (int j = 0; j < 2; ++j) acc[t][i][j] = 0.0f;

    const int tbw = wv * B_SZ + b;    // staging timestep-batch for this wave

    float4 wreg0, wreg1;
    u32 xa = 0, xb = 0;
    float mreg = 1.0f;
    float4 xfa, xfb;

    auto prefetch = [&](int kt) {
        const float* wp = W + (size_t)(coBase + wr) * K + kt * 16 + wk8;
        wreg0 = *reinterpret_cast<const float4*>(wp);
        wreg1 = *reinterpret_cast<const float4*>(wp + 4);
        if constexpr (BSRC <= 1) {
            const u8* xp = (const u8*)Xv + (size_t)tbw * K * N_SP
                           + (size_t)(kt * 16 + xrow) * N_SP + n0blk + xn0;
            const uint2 u = *reinterpret_cast<const uint2*>(xp);
            xa = u.x; xb = u.y;
            if constexpr (BSRC == 1)
                mreg = kvsf[(size_t)tbw * K + kt * 16 + xrow];
        } else {
            const float* xp = (const float*)Xv + (size_t)tbw * K * N_SP
                              + (size_t)(kt * 16 + xrow) * N_SP + n0blk + xn0;
            xfa = *reinterpret_cast<const float4*>(xp);
            xfb = *reinterpret_cast<const float4*>(xp + 4);
        }
    };

    prefetch(0);

    for (int kt = 0; kt < KT; ++kt) {
        __syncthreads();    // previous tile's compute done; LDS reusable
        As[wk8 + 0][wr] = wreg0.x;
        As[wk8 + 1][wr] = wreg0.y;
        As[wk8 + 2][wr] = wreg0.z;
        As[wk8 + 3][wr] = wreg0.w;
        As[wk8 + 4][wr] = wreg1.x;
        As[wk8 + 5][wr] = wreg1.y;
        As[wk8 + 6][wr] = wreg1.z;
        As[wk8 + 7][wr] = wreg1.w;
        {
            float4 s0, s1;
            if constexpr (BSRC <= 1) {
                s0.x = (float)( xa        & 0xFFu);
                s0.y = (float)((xa >> 8 ) & 0xFFu);
                s0.z = (float)((xa >> 16) & 0xFFu);
                s0.w = (float)( xa >> 24        );
                s1.x = (float)( xb        & 0xFFu);
                s1.y = (float)((xb >> 8 ) & 0xFFu);
                s1.z = (float)((xb >> 16) & 0xFFu);
                s1.w = (float)( xb >> 24        );
                if constexpr (BSRC == 1) {
                    s0.x *= mreg; s0.y *= mreg; s0.z *= mreg; s0.w *= mreg;   // 0/1 x 0/1: exact
                    s1.x *= mreg; s1.y *= mreg; s1.z *= mreg; s1.w *= mreg;
                }
            } else {
                s0 = xfa; s1 = xfb;
            }
            *reinterpret_cast<float4*>(&Xs[wv][xrow][xn0]) = s0;
            *reinterpret_cast<float4*>(&Xs[wv][xrow][xn0 + 4]) = s1;
        }
        __syncthreads();
        if (kt + 1 < KT) prefetch(kt + 1);   // overlaps with compute below

        #pragma unroll
        for (int kk = 0; kk < 16; ++kk) {
            float4 a0 = *reinterpret_cast<const float4*>(&As[kk][ty * 8]);
            float4 a1 = *reinterpret_cast<const float4*>(&As[kk][ty * 8 + 4]);
            float wa[8] = {a0.x, a0.y, a0.z, a0.w, a1.x, a1.y, a1.z, a1.w};
            #pragma unroll
            for (int t = 0; t < 4; ++t) {
                float2 xv = *reinterpret_cast<const float2*>(&Xs[t][kk][tx * 2]);
                float xw[2] = {xv.x, xv.y};
                #pragma unroll
                for (int i = 0; i < 8; ++i)
                    #pragma unroll
                    for (int j = 0; j < 2; ++j)
                        acc[t][i][j] += wa[i] * xw[j];   // ascending-k, single acc
            }
        }
    }

    // epilogue: LIF chain over t (ascending), expressions identical to round 2.
    #pragma unroll
    for (int i = 0; i < 8; ++i) {
        const int co = coBase + ty * 8 + i;
        float v[2] = {0.0f, 0.0f};
        #pragma unroll
        for (int t = 0; t < 4; ++t) {
            const int tb = t * B_SZ + b;
            const size_t off = ((size_t)tb * CO + co) * N_SP + n0blk + tx * 2;
            if constexpr (MODE == 0) {
                u32 pk = 0;
                #pragma unroll
                for (int e = 0; e < 2; ++e) {
                    const float y = acc[t][i][e] * scale[i] + shift[i];
                    v[e] += (y - v[e]) * 0.5f;
                    const u32 s = (v[e] >= 0.5f) ? 1u : 0u;
                    v[e] = s ? 0.0f : v[e];
                    pk |= s << (8 * e);
                }
                *reinterpret_cast<u16*>((u8*)Yv + off) = (u16)pk;
            } else if constexpr (MODE == 1) {
                const float2 r0 = *reinterpret_cast<const float2*>(res + off);
                float2 s0;
                s0.x = acc[t][i][0] * scale[i] + shift[i] + r0.x;
                s0.y = acc[t][i][1] * scale[i] + shift[i] + r0.y;
                *reinterpret_cast<float2*>((float*)Yv + off) = s0;
            } else {
                float* op = (float*)Yv + off;
                const float2 r0 = *reinterpret_cast<const float2*>(op);
                float rr2[2] = {r0.x, r0.y};
                float o[2];
                #pragma unroll
                for (int e = 0; e < 2; ++e) {
                    const float y = acc[t][i][e] * scale[i] + shift[i];
                    v[e] += (y - v[e]) * 0.5f;
                    const u32 s = (v[e] >= 0.5f) ? 1u : 0u;
                    v[e] = s ? 0.0f : v[e];
                    o[e] = rr2[e] + (s ? 1.0f : 0.0f);
                }
                float2 s0 = {o[0], o[1]};
                *reinterpret_cast<float2*>(op) = s0;
            }
        }
    }
}

// ---------------------------------------------------------------------------
// kv_raw[row=tb*C+c] = sum_n k*v  (exact integer; round-2 verbatim)
// ---------------------------------------------------------------------------
__global__ __launch_bounds__(256) void kv_reduce(const u8* __restrict__ ks,
                                                 const u8* __restrict__ vs,
                                                 float* __restrict__ kv)
{
    const int row = blockIdx.x * 4 + (threadIdx.x >> 6);  // [0, T*B*C)
    const int lane = threadIdx.x & 63;
    const u8* kp = ks + (size_t)row * N_SP;
    const u8* vp = vs + (size_t)row * N_SP;
    int acc = 0;
    #pragma unroll
    for (int n = 0; n < N_SP; n += 256) {
        uchar4 a = *reinterpret_cast<const uchar4*>(kp + n + lane * 4);
        uchar4 c = *reinterpret_cast<const uchar4*>(vp + n + lane * 4);
        acc += (a.x & c.x) + (a.y & c.y) + (a.z & c.z) + (a.w & c.w);
    }
    #pragma unroll
    for (int off = 32; off; off >>= 1) acc += __shfl_down(acc, off, 64);
    if (lane == 0) kv[row] = (float)acc;
}

// ---------------------------------------------------------------------------
// talking heads (8x8 over heads) + LIF -> kvs float {0,1}  (round-2 verbatim)
// ---------------------------------------------------------------------------
__global__ __launch_bounds__(256) void th_lif(const float* __restrict__ kvraw,
                                              const float* __restrict__ th,
                                              float* __restrict__ kvs)
{
    const int i = blockIdx.x * 256 + threadIdx.x;   // [0, B*C)
    const int b = i >> 9;
    const int c = i & 511;
    const int g = c >> 6;
    const int dd = c & 63;
    float v = 0.0f;
    #pragma unroll
    for (int t = 0; t < T_STEPS; ++t) {
        const float* base = kvraw + ((size_t)t * B_SZ + b) * C_IN;
        float x = 0.0f;
        #pragma unroll
        for (int hh = 0; hh < 8; ++hh)
            x += base[hh * 64 + dd] * th[g * 8 + hh];
        v += (x - v) * 0.5f;
        const float s = (v >= 0.5f) ? 1.0f : 0.0f;
        kvs[((size_t)t * B_SZ + b) * C_IN + c] = s;
        v = (s != 0.0f) ? 0.0f : v;
    }
}

extern "C" void kernel_launch(void* const* d_in, const int* in_sizes, int n_in,
                              void* d_out, int out_size, void* d_ws, size_t ws_size,
                              hipStream_t stream)
{
    const float* x       = (const float*)d_in[0];
    const float* q_w     = (const float*)d_in[1];
    const float* q_bn    = (const float*)d_in[2];
    const float* k_w     = (const float*)d_in[3];
    const float* k_bn    = (const float*)d_in[4];
    const float* v_w     = (const float*)d_in[5];
    const float* v_bn    = (const float*)d_in[6];
    const float* th_w    = (const float*)d_in[7];
    const float* proj_w  = (const float*)d_in[8];
    const float* proj_b  = (const float*)d_in[9];
    const float* proj_bn = (const float*)d_in[10];
    const float* fc1_w   = (const float*)d_in[11];
    const float* fc1_b   = (const float*)d_in[12];
    const float* fc1_bn  = (const float*)d_in[13];
    const float* fc2_w   = (const float*)d_in[14];
    const float* fc2_b   = (const float*)d_in[15];
    const float* fc2_bn  = (const float*)d_in[16];
    float* out = (float*)d_out;

    // workspace: round-2/6/9/13's proven 64 MiB + 128 KiB map
    u8* ws = (u8*)d_ws;
    const size_t SLOT = (size_t)T_STEPS * S_C;        // 16 MiB per u8 slot
    u8* xs = ws;                    // [TB][C][N] u8
    u8* qs = ws + SLOT;
    u8* ks = ws + 2 * SLOT;
    u8* vs = ws + 3 * SLOT;
    float* kvraw = (float*)(ws + 4 * SLOT);                 // [TB][C] f32 (64 KiB)
    float* kvsf  = kvraw + (size_t)T_STEPS * B_SZ * C_IN;   // [TB][C] f32 (64 KiB)
    u8* hdn = ws;                   // [TB][Ch][N] u8 = 64 MiB, reuses xs..vs (dead by fc1)

    // 1. xs = lif(x)
    lif_x_kernel<<<(int)(S_C / 256), 256, 0, stream>>>(x, xs);

    // 2. q/k/v = lif(bn(conv(xs)))  — fused triple GEMM, t-folded, 128co tile
    //    grid = CBTOT(4*3=12) * 32 nblk * 8 b = 3072
    mm<0, 0, false, 512, 512, 3><<<3072, 256, 0, stream>>>(
        q_w, k_w, v_w, xs, q_bn, k_bn, v_bn, nullptr, nullptr, nullptr, qs, ks, vs);

    // 3. kv_raw = rowwise dot(k, v); 4. talking heads + lif -> kvs (float 0/1)
    kv_reduce<<<(T_STEPS * B_SZ * C_IN) / 4, 256, 0, stream>>>(ks, vs, kvraw);
    th_lif<<<(B_SZ * C_IN) / 256, 256, 0, stream>>>(kvraw, th_w, kvsf);

    // 5. xout = bn(proj(q * kvs) + b) + x  -> d_out;  grid 4*32*8 = 1024
    mm<1, 1, true, 512, 512, 1><<<1024, 256, 0, stream>>>(
        proj_w, nullptr, nullptr, qs, proj_bn, nullptr, nullptr, proj_b, kvsf, x,
        out, nullptr, nullptr);

    // 6. hdn = lif(bn(fc1(xout) + b));  grid 16*32*8 = 4096
    mm<0, 2, true, 512, 2048, 1><<<4096, 256, 0, stream>>>(
        fc1_w, nullptr, nullptr, out, fc1_bn, nullptr, nullptr, fc1_b, nullptr, nullptr,
        hdn, nullptr, nullptr);

    // 7. out = lif(bn(fc2(hdn) + b)) + xout  (in place on d_out);  grid 1024
    mm<2, 0, true, 2048, 512, 1><<<1024, 256, 0, stream>>>(
        fc2_w, nullptr, nullptr, hdn, fc2_bn, nullptr, nullptr, fc2_b, nullptr, nullptr,
        out, nullptr, nullptr);
}

// Round 16
// 2456.070 us; speedup vs baseline: 1.0682x; 1.0156x over previous
//
#include <hip/hip_runtime.h>

typedef unsigned char u8;
typedef unsigned int u32;

#define T_STEPS 4
#define B_SZ 8
#define C_IN 512
#define CH 2048
#define N_SP 1024
#define S_C ((size_t)B_SZ * C_IN * N_SP)    // elems per timestep

// ---------------------------------------------------------------------------
// lif_x: x [T,B,C,N] fp32 -> xs u8 spikes, same flat layout (round-2 verbatim).
// ---------------------------------------------------------------------------
__global__ __launch_bounds__(256) void lif_x_kernel(const float* __restrict__ in,
                                                    u8* __restrict__ out)
{
    size_t i = (size_t)blockIdx.x * 256 + threadIdx.x;
    float v = 0.0f;
    #pragma unroll
    for (int t = 0; t < T_STEPS; ++t) {
        float x = in[(size_t)t * S_C + i];
        v += (x - v) * 0.5f;
        u8 s = (v >= 0.5f) ? 1 : 0;
        out[(size_t)t * S_C + i] = s;
        v = s ? 0.0f : v;
    }
}

// ---------------------------------------------------------------------------
// Fused GEMM + BN (+bias) + LIF, fp32, T-FOLDED + WAVE-AUTONOMOUS (round 16):
//   Block = 4 waves, tile 64co x 64n x 4t (round-13 geometry & grids).
//   Each wave owns a PRIVATE LDS region: its own W copy (64co x 8k) and its
//   own X slice (4t x 8k x 16n).  No data crosses waves ->
//   ZERO __syncthreads() anywhere.  Write->read ordering within a wave is
//   enforced by compiler lgkmcnt on the may-aliasing __shared__ arrays;
//   a wave's own stall overlaps with the other resident waves' issue.
//   (Rounds 9-15 measured the 2-barriers-per-k-tile drain as the ~30% gap.)
//   BK=8 keeps prefetch registers small (W 8, X 2-8) -> VGPR ~100.
// Per output element: ascending-k (tiles ascend, kk ascends), single fp32
// accumulator; epilogue LIF chain over t identical to rounds 2/6/9/13
// -> bit-identical output.
// Layouts: X [TB][K][N], W [CO][K] fp32, Y [TB][CO][N].
// MODE 0: LIF -> u8 spikes. MODE 1: y + res -> f32. MODE 2: LIF spike + in-place res -> f32.
// BSRC 0: u8 X. BSRC 1: u8 X * kvsf[t][k] at staging (proj mask). BSRC 2: f32 X (fc1).
// NOTE: no min-waves hint (round 8: (256,4) clamps to 64 VGPR and spills).
// ---------------------------------------------------------------------------
template<int MODE, int BSRC, bool BIAS, int K, int CO, int NSEL>
__global__ __launch_bounds__(256) void mm(
    const float* __restrict__ W0, const float* __restrict__ W1, const float* __restrict__ W2,
    const void* __restrict__ Xv,
    const float* __restrict__ bn0, const float* __restrict__ bn1, const float* __restrict__ bn2,
    const float* __restrict__ bias,
    const float* __restrict__ kvsf,
    const float* __restrict__ res,
    void* Y0, void* Y1, void* Y2)
{
    constexpr int NB_CB = CO / 64;
    constexpr int KT = K / 8;

    __shared__ float Ws[4][8][66];      // [wave][k][co]   per-wave private
    __shared__ float Xs[4][4][8][18];   // [wave][t][k][n] per-wave private

    const int bid = blockIdx.x;
    const int nblk = bid % 16;          // round-13 grid order (FETCH-proven)
    int slot = bid / 16;
    const int cb = slot % NB_CB; slot /= NB_CB;
    const int sel = (NSEL > 1) ? (slot % NSEL) : 0;
    const int b   = (NSEL > 1) ? (slot / NSEL) : slot;

    const float* W   = (NSEL == 1 || sel == 0) ? W0  : (sel == 1 ? W1  : W2);
    const float* bnp = (NSEL == 1 || sel == 0) ? bn0 : (sel == 1 ? bn1 : bn2);
    void* Yv         = (NSEL == 1 || sel == 0) ? Y0  : (sel == 1 ? Y1  : Y2);

    const int coBase = cb * 64;
    const int tid = threadIdx.x;
    const int wv = tid >> 6;            // wave id 0..3
    const int lane = tid & 63;
    const int cog = lane >> 2;          // 0..15 : 4-co group
    const int ng = lane & 3;            // 0..3  : 4-n group
    const int nW = nblk * 64 + wv * 16; // wave's n base (16 wide)

    // X staging decode: lane -> (t, k-in-tile, n-seg)
    const int xr = lane >> 1;           // 0..31
    const int xt = xr >> 3;             // t
    const int xk = xr & 7;              // k in tile
    const int xseg = (lane & 1) * 8;    // n seg (8 elems)

    // BN constants (round-2 expressions)
    float scale[4], shift[4];
    #pragma unroll
    for (int i = 0; i < 4; ++i) {
        const int co = coBase + cog * 4 + i;
        const float g = bnp[co], be = bnp[CO + co];
        const float mn = bnp[2 * CO + co], vr = bnp[3 * CO + co];
        scale[i] = g / sqrtf(vr + 1e-5f);
        shift[i] = be - mn * scale[i];
        if (BIAS) shift[i] += bias[co] * scale[i];
    }

    float acc[4][4][4];   // [t][co i][n j]
    #pragma unroll
    for (int t = 0; t < 4; ++t)
        #pragma unroll
        for (int i = 0; i < 4; ++i)
            #pragma unroll
            for (int j = 0; j < 4; ++j) acc[t][i][j] = 0.0f;

    // per-lane staging bases
    const float* wRow = W + (size_t)(coBase + lane) * K;      // lane stages co row = lane
    const int tbx = xt * B_SZ + b;                            // staging timestep-batch
    const u8* xuBase = (const u8*)Xv + (size_t)tbx * K * N_SP + nW + xseg;
    const float* xfBase = (const float*)Xv + (size_t)tbx * K * N_SP + nW + xseg;

    float wpre[8];
    u32 xa = 0, xb = 0;
    float mreg = 1.0f;
    float4 xfa, xfb;

    auto prefetch = [&](int kt) {
        const float* wp = wRow + kt * 8;
        *reinterpret_cast<float4*>(&wpre[0]) = *reinterpret_cast<const float4*>(wp);
        *reinterpret_cast<float4*>(&wpre[4]) = *reinterpret_cast<const float4*>(wp + 4);
        const int krow = kt * 8 + xk;
        if constexpr (BSRC <= 1) {
            const uint2 u = *reinterpret_cast<const uint2*>(xuBase + (size_t)krow * N_SP);
            xa = u.x; xb = u.y;
            if constexpr (BSRC == 1)
                mreg = kvsf[(size_t)tbx * K + krow];
        } else {
            const float* xp = xfBase + (size_t)krow * N_SP;
            xfa = *reinterpret_cast<const float4*>(xp);
            xfb = *reinterpret_cast<const float4*>(xp + 4);
        }
    };

    prefetch(0);

    #pragma unroll 1
    for (int kt = 0; kt < KT; ++kt) {
        // stage W (8 scalar column writes: lanes spread 2-way over banks, free)
        #pragma unroll
        for (int j = 0; j < 8; ++j) Ws[wv][j][lane] = wpre[j];
        // stage X (unpack u8 -> f32 here; mask is 0/1 x 0/1, exact)
        {
            float4 s0, s1;
            if constexpr (BSRC <= 1) {
                s0.x = (float)( xa        & 0xFFu);
                s0.y = (float)((xa >> 8 ) & 0xFFu);
                s0.z = (float)((xa >> 16) & 0xFFu);
                s0.w = (float)( xa >> 24        );
                s1.x = (float)( xb        & 0xFFu);
                s1.y = (float)((xb >> 8 ) & 0xFFu);
                s1.z = (float)((xb >> 16) & 0xFFu);
                s1.w = (float)( xb >> 24        );
                if constexpr (BSRC == 1) {
                    s0.x *= mreg; s0.y *= mreg; s0.z *= mreg; s0.w *= mreg;
                    s1.x *= mreg; s1.y *= mreg; s1.z *= mreg; s1.w *= mreg;
                }
            } else {
                s0 = xfa; s1 = xfb;
            }
            *reinterpret_cast<float4*>(&Xs[wv][xt][xk][xseg]) = s0;
            *reinterpret_cast<float4*>(&Xs[wv][xt][xk][xseg + 4]) = s1;
        }
        if (kt + 1 < KT) prefetch(kt + 1);   // global loads fly during compute

        // compute: reads follow writes in this wave's program order; compiler
        // inserts the lgkmcnt wait (same __shared__ arrays). No cross-wave data.
        #pragma unroll
        for (int kk = 0; kk < 8; ++kk) {
            float4 av = *reinterpret_cast<const float4*>(&Ws[wv][kk][cog * 4]);
            float wa[4] = {av.x, av.y, av.z, av.w};
            #pragma unroll
            for (int t = 0; t < 4; ++t) {
                float4 xq = *reinterpret_cast<const float4*>(&Xs[wv][t][kk][ng * 4]);
                float xw[4] = {xq.x, xq.y, xq.z, xq.w};
                #pragma unroll
                for (int i = 0; i < 4; ++i)
                    #pragma unroll
                    for (int j = 0; j < 4; ++j)
                        acc[t][i][j] += wa[i] * xw[j];   // ascending-k, single acc
            }
        }
    }

    // epilogue: LIF chain over t (ascending), expressions identical to round 2.
    #pragma unroll
    for (int i = 0; i < 4; ++i) {
        const int co = coBase + cog * 4 + i;
        float v[4] = {0.0f, 0.0f, 0.0f, 0.0f};
        #pragma unroll
        for (int t = 0; t < 4; ++t) {
            const int tb = t * B_SZ + b;
            const size_t off = ((size_t)tb * CO + co) * N_SP + nW + ng * 4;
            if constexpr (MODE == 0) {
                u32 pk = 0;
                #pragma unroll
                for (int e = 0; e < 4; ++e) {
                    const float y = acc[t][i][e] * scale[i] + shift[i];
                    v[e] += (y - v[e]) * 0.5f;
                    const u32 s = (v[e] >= 0.5f) ? 1u : 0u;
                    v[e] = s ? 0.0f : v[e];
                    pk |= s << (8 * e);
                }
                *reinterpret_cast<u32*>((u8*)Yv + off) = pk;
            } else if constexpr (MODE == 1) {
                float4 r0 = *reinterpret_cast<const float4*>(res + off);
                float rr2[4] = {r0.x, r0.y, r0.z, r0.w};
                float o[4];
                #pragma unroll
                for (int e = 0; e < 4; ++e)
                    o[e] = acc[t][i][e] * scale[i] + shift[i] + rr2[e];
                float4 s0 = {o[0], o[1], o[2], o[3]};
                *reinterpret_cast<float4*>((float*)Yv + off) = s0;
            } else {
                float* op = (float*)Yv + off;
                float4 r0 = *reinterpret_cast<const float4*>(op);
                float rr2[4] = {r0.x, r0.y, r0.z, r0.w};
                float o[4];
                #pragma unroll
                for (int e = 0; e < 4; ++e) {
                    const float y = acc[t][i][e] * scale[i] + shift[i];
                    v[e] += (y - v[e]) * 0.5f;
                    const u32 s = (v[e] >= 0.5f) ? 1u : 0u;
                    v[e] = s ? 0.0f : v[e];
                    o[e] = rr2[e] + (s ? 1.0f : 0.0f);
                }
                float4 s0 = {o[0], o[1], o[2], o[3]};
                *reinterpret_cast<float4*>(op) = s0;
            }
        }
    }
}

// ---------------------------------------------------------------------------
// kv_raw[row=tb*C+c] = sum_n k*v  (exact integer; round-2 verbatim)
// ---------------------------------------------------------------------------
__global__ __launch_bounds__(256) void kv_reduce(const u8* __restrict__ ks,
                                                 const u8* __restrict__ vs,
                                                 float* __restrict__ kv)
{
    const int row = blockIdx.x * 4 + (threadIdx.x >> 6);  // [0, T*B*C)
    const int lane = threadIdx.x & 63;
    const u8* kp = ks + (size_t)row * N_SP;
    const u8* vp = vs + (size_t)row * N_SP;
    int acc = 0;
    #pragma unroll
    for (int n = 0; n < N_SP; n += 256) {
        uchar4 a = *reinterpret_cast<const uchar4*>(kp + n + lane * 4);
        uchar4 c = *reinterpret_cast<const uchar4*>(vp + n + lane * 4);
        acc += (a.x & c.x) + (a.y & c.y) + (a.z & c.z) + (a.w & c.w);
    }
    #pragma unroll
    for (int off = 32; off; off >>= 1) acc += __shfl_down(acc, off, 64);
    if (lane == 0) kv[row] = (float)acc;
}

// ---------------------------------------------------------------------------
// talking heads (8x8 over heads) + LIF -> kvs float {0,1}  (round-2 verbatim)
// ---------------------------------------------------------------------------
__global__ __launch_bounds__(256) void th_lif(const float* __restrict__ kvraw,
                                              const float* __restrict__ th,
                                              float* __restrict__ kvs)
{
    const int i = blockIdx.x * 256 + threadIdx.x;   // [0, B*C)
    const int b = i >> 9;
    const int c = i & 511;
    const int g = c >> 6;
    const int dd = c & 63;
    float v = 0.0f;
    #pragma unroll
    for (int t = 0; t < T_STEPS; ++t) {
        const float* base = kvraw + ((size_t)t * B_SZ + b) * C_IN;
        float x = 0.0f;
        #pragma unroll
        for (int hh = 0; hh < 8; ++hh)
            x += base[hh * 64 + dd] * th[g * 8 + hh];
        v += (x - v) * 0.5f;
        const float s = (v >= 0.5f) ? 1.0f : 0.0f;
        kvs[((size_t)t * B_SZ + b) * C_IN + c] = s;
        v = (s != 0.0f) ? 0.0f : v;
    }
}

extern "C" void kernel_launch(void* const* d_in, const int* in_sizes, int n_in,
                              void* d_out, int out_size, void* d_ws, size_t ws_size,
                              hipStream_t stream)
{
    const float* x       = (const float*)d_in[0];
    const float* q_w     = (const float*)d_in[1];
    const float* q_bn    = (const float*)d_in[2];
    const float* k_w     = (const float*)d_in[3];
    const float* k_bn    = (const float*)d_in[4];
    const float* v_w     = (const float*)d_in[5];
    const float* v_bn    = (const float*)d_in[6];
    const float* th_w    = (const float*)d_in[7];
    const float* proj_w  = (const float*)d_in[8];
    const float* proj_b  = (const float*)d_in[9];
    const float* proj_bn = (const float*)d_in[10];
    const float* fc1_w   = (const float*)d_in[11];
    const float* fc1_b   = (const float*)d_in[12];
    const float* fc1_bn  = (const float*)d_in[13];
    const float* fc2_w   = (const float*)d_in[14];
    const float* fc2_b   = (const float*)d_in[15];
    const float* fc2_bn  = (const float*)d_in[16];
    float* out = (float*)d_out;

    // workspace: round-2/6/9/13's proven 64 MiB + 128 KiB map
    u8* ws = (u8*)d_ws;
    const size_t SLOT = (size_t)T_STEPS * S_C;        // 16 MiB per u8 slot
    u8* xs = ws;                    // [TB][C][N] u8
    u8* qs = ws + SLOT;
    u8* ks = ws + 2 * SLOT;
    u8* vs = ws + 3 * SLOT;
    float* kvraw = (float*)(ws + 4 * SLOT);                 // [TB][C] f32 (64 KiB)
    float* kvsf  = kvraw + (size_t)T_STEPS * B_SZ * C_IN;   // [TB][C] f32 (64 KiB)
    u8* hdn = ws;                   // [TB][Ch][N] u8 = 64 MiB, reuses xs..vs (dead by fc1)

    // 1. xs = lif(x)
    lif_x_kernel<<<(int)(S_C / 256), 256, 0, stream>>>(x, xs);

    // 2. q/k/v = lif(bn(conv(xs)))  — fused triple GEMM, t-folded, barrier-free
    //    grid = 16 nblk * 8 cb * 3 sel * 8 b = 3072
    mm<0, 0, false, 512, 512, 3><<<3072, 256, 0, stream>>>(
        q_w, k_w, v_w, xs, q_bn, k_bn, v_bn, nullptr, nullptr, nullptr, qs, ks, vs);

    // 3. kv_raw = rowwise dot(k, v); 4. talking heads + lif -> kvs (float 0/1)
    kv_reduce<<<(T_STEPS * B_SZ * C_IN) / 4, 256, 0, stream>>>(ks, vs, kvraw);
    th_lif<<<(B_SZ * C_IN) / 256, 256, 0, stream>>>(kvraw, th_w, kvsf);

    // 5. xout = bn(proj(q * kvs) + b) + x  -> d_out;  grid 16*8*8 = 1024
    mm<1, 1, true, 512, 512, 1><<<1024, 256, 0, stream>>>(
        proj_w, nullptr, nullptr, qs, proj_bn, nullptr, nullptr, proj_b, kvsf, x,
        out, nullptr, nullptr);

    // 6. hdn = lif(bn(fc1(xout) + b));  grid 16*32*8 = 4096
    mm<0, 2, true, 512, 2048, 1><<<4096, 256, 0, stream>>>(
        fc1_w, nullptr, nullptr, out, fc1_bn, nullptr, nullptr, fc1_b, nullptr, nullptr,
        hdn, nullptr, nullptr);

    // 7. out = lif(bn(fc2(hdn) + b)) + xout  (in place on d_out);  grid 1024
    mm<2, 0, true, 2048, 512, 1><<<1024, 256, 0, stream>>>(
        fc2_w, nullptr, nullptr, hdn, fc2_bn, nullptr, nullptr, fc2_b, nullptr, nullptr,
        out, nullptr, nullptr);
}

// Round 17
// 2449.923 us; speedup vs baseline: 1.0709x; 1.0025x over previous
//
#include <hip/hip_runtime.h>

typedef unsigned char u8;
typedef unsigned int u32;

#define T_STEPS 4
#define B_SZ 8
#define C_IN 512
#define CH 2048
#define N_SP 1024
#define S_C ((size_t)B_SZ * C_IN * N_SP)    // elems per timestep

// ---------------------------------------------------------------------------
// lif_x: x [T,B,C,N] fp32 -> xs u8 spikes, same flat layout (round-2 verbatim).
// ---------------------------------------------------------------------------
__global__ __launch_bounds__(256) void lif_x_kernel(const float* __restrict__ in,
                                                    u8* __restrict__ out)
{
    size_t i = (size_t)blockIdx.x * 256 + threadIdx.x;
    float v = 0.0f;
    #pragma unroll
    for (int t = 0; t < T_STEPS; ++t) {
        float x = in[(size_t)t * S_C + i];
        v += (x - v) * 0.5f;
        u8 s = (v >= 0.5f) ? 1 : 0;
        out[(size_t)t * S_C + i] = s;
        v = s ? 0.0f : v;
    }
}

// ---------------------------------------------------------------------------
// Fused GEMM + BN (+bias) + LIF, fp32, T-FOLDED + WAVE-AUTONOMOUS (round 16):
//   Block = 4 waves, tile 64co x 64n x 4t (round-13 geometry & grids).
//   Each wave owns a PRIVATE LDS region: its own W copy (64co x 8k) and its
//   own X slice (4t x 8k x 16n).  No data crosses waves ->
//   ZERO __syncthreads() anywhere.  Write->read ordering within a wave is
//   enforced by compiler lgkmcnt on the may-aliasing __shared__ arrays;
//   a wave's own stall overlaps with the other resident waves' issue.
//   (Rounds 9-15 measured the 2-barriers-per-k-tile drain as the ~30% gap.)
//   BK=8 keeps prefetch registers small (W 8, X 2-8) -> VGPR ~100.
// Per output element: ascending-k (tiles ascend, kk ascends), single fp32
// accumulator; epilogue LIF chain over t identical to rounds 2/6/9/13
// -> bit-identical output.
// Layouts: X [TB][K][N], W [CO][K] fp32, Y [TB][CO][N].
// MODE 0: LIF -> u8 spikes. MODE 1: y + res -> f32. MODE 2: LIF spike + in-place res -> f32.
// BSRC 0: u8 X. BSRC 1: u8 X * kvsf[t][k] at staging (proj mask). BSRC 2: f32 X (fc1).
// NOTE: no min-waves hint (round 8: (256,4) clamps to 64 VGPR and spills).
// ---------------------------------------------------------------------------
template<int MODE, int BSRC, bool BIAS, int K, int CO, int NSEL>
__global__ __launch_bounds__(256) void mm(
    const float* __restrict__ W0, const float* __restrict__ W1, const float* __restrict__ W2,
    const void* __restrict__ Xv,
    const float* __restrict__ bn0, const float* __restrict__ bn1, const float* __restrict__ bn2,
    const float* __restrict__ bias,
    const float* __restrict__ kvsf,
    const float* __restrict__ res,
    void* Y0, void* Y1, void* Y2)
{
    constexpr int NB_CB = CO / 64;
    constexpr int KT = K / 8;

    __shared__ float Ws[4][8][66];      // [wave][k][co]   per-wave private
    __shared__ float Xs[4][4][8][18];   // [wave][t][k][n] per-wave private

    const int bid = blockIdx.x;
    const int nblk = bid % 16;          // round-13 grid order (FETCH-proven)
    int slot = bid / 16;
    const int cb = slot % NB_CB; slot /= NB_CB;
    const int sel = (NSEL > 1) ? (slot % NSEL) : 0;
    const int b   = (NSEL > 1) ? (slot / NSEL) : slot;

    const float* W   = (NSEL == 1 || sel == 0) ? W0  : (sel == 1 ? W1  : W2);
    const float* bnp = (NSEL == 1 || sel == 0) ? bn0 : (sel == 1 ? bn1 : bn2);
    void* Yv         = (NSEL == 1 || sel == 0) ? Y0  : (sel == 1 ? Y1  : Y2);

    const int coBase = cb * 64;
    const int tid = threadIdx.x;
    const int wv = tid >> 6;            // wave id 0..3
    const int lane = tid & 63;
    const int cog = lane >> 2;          // 0..15 : 4-co group
    const int ng = lane & 3;            // 0..3  : 4-n group
    const int nW = nblk * 64 + wv * 16; // wave's n base (16 wide)

    // X staging decode: lane -> (t, k-in-tile, n-seg)
    const int xr = lane >> 1;           // 0..31
    const int xt = xr >> 3;             // t
    const int xk = xr & 7;              // k in tile
    const int xseg = (lane & 1) * 8;    // n seg (8 elems)

    // BN constants (round-2 expressions)
    float scale[4], shift[4];
    #pragma unroll
    for (int i = 0; i < 4; ++i) {
        const int co = coBase + cog * 4 + i;
        const float g = bnp[co], be = bnp[CO + co];
        const float mn = bnp[2 * CO + co], vr = bnp[3 * CO + co];
        scale[i] = g / sqrtf(vr + 1e-5f);
        shift[i] = be - mn * scale[i];
        if (BIAS) shift[i] += bias[co] * scale[i];
    }

    float acc[4][4][4];   // [t][co i][n j]
    #pragma unroll
    for (int t = 0; t < 4; ++t)
        #pragma unroll
        for (int i = 0; i < 4; ++i)
            #pragma unroll
            for (int j = 0; j < 4; ++j) acc[t][i][j] = 0.0f;

    // per-lane staging bases
    const float* wRow = W + (size_t)(coBase + lane) * K;      // lane stages co row = lane
    const int tbx = xt * B_SZ + b;                            // staging timestep-batch
    const u8* xuBase = (const u8*)Xv + (size_t)tbx * K * N_SP + nW + xseg;
    const float* xfBase = (const float*)Xv + (size_t)tbx * K * N_SP + nW + xseg;

    float wpre[8];
    u32 xa = 0, xb = 0;
    float mreg = 1.0f;
    float4 xfa, xfb;

    auto prefetch = [&](int kt) {
        const float* wp = wRow + kt * 8;
        *reinterpret_cast<float4*>(&wpre[0]) = *reinterpret_cast<const float4*>(wp);
        *reinterpret_cast<float4*>(&wpre[4]) = *reinterpret_cast<const float4*>(wp + 4);
        const int krow = kt * 8 + xk;
        if constexpr (BSRC <= 1) {
            const uint2 u = *reinterpret_cast<const uint2*>(xuBase + (size_t)krow * N_SP);
            xa = u.x; xb = u.y;
            if constexpr (BSRC == 1)
                mreg = kvsf[(size_t)tbx * K + krow];
        } else {
            const float* xp = xfBase + (size_t)krow * N_SP;
            xfa = *reinterpret_cast<const float4*>(xp);
            xfb = *reinterpret_cast<const float4*>(xp + 4);
        }
    };

    prefetch(0);

    #pragma unroll 1
    for (int kt = 0; kt < KT; ++kt) {
        // stage W (8 scalar column writes: lanes spread 2-way over banks, free)
        #pragma unroll
        for (int j = 0; j < 8; ++j) Ws[wv][j][lane] = wpre[j];
        // stage X (unpack u8 -> f32 here; mask is 0/1 x 0/1, exact)
        {
            float4 s0, s1;
            if constexpr (BSRC <= 1) {
                s0.x = (float)( xa        & 0xFFu);
                s0.y = (float)((xa >> 8 ) & 0xFFu);
                s0.z = (float)((xa >> 16) & 0xFFu);
                s0.w = (float)( xa >> 24        );
                s1.x = (float)( xb        & 0xFFu);
                s1.y = (float)((xb >> 8 ) & 0xFFu);
                s1.z = (float)((xb >> 16) & 0xFFu);
                s1.w = (float)( xb >> 24        );
                if constexpr (BSRC == 1) {
                    s0.x *= mreg; s0.y *= mreg; s0.z *= mreg; s0.w *= mreg;
                    s1.x *= mreg; s1.y *= mreg; s1.z *= mreg; s1.w *= mreg;
                }
            } else {
                s0 = xfa; s1 = xfb;
            }
            *reinterpret_cast<float4*>(&Xs[wv][xt][xk][xseg]) = s0;
            *reinterpret_cast<float4*>(&Xs[wv][xt][xk][xseg + 4]) = s1;
        }
        if (kt + 1 < KT) prefetch(kt + 1);   // global loads fly during compute

        // compute: reads follow writes in this wave's program order; compiler
        // inserts the lgkmcnt wait (same __shared__ arrays). No cross-wave data.
        #pragma unroll
        for (int kk = 0; kk < 8; ++kk) {
            float4 av = *reinterpret_cast<const float4*>(&Ws[wv][kk][cog * 4]);
            float wa[4] = {av.x, av.y, av.z, av.w};
            #pragma unroll
            for (int t = 0; t < 4; ++t) {
                float4 xq = *reinterpret_cast<const float4*>(&Xs[wv][t][kk][ng * 4]);
                float xw[4] = {xq.x, xq.y, xq.z, xq.w};
                #pragma unroll
                for (int i = 0; i < 4; ++i)
                    #pragma unroll
                    for (int j = 0; j < 4; ++j)
                        acc[t][i][j] += wa[i] * xw[j];   // ascending-k, single acc
            }
        }
    }

    // epilogue: LIF chain over t (ascending), expressions identical to round 2.
    #pragma unroll
    for (int i = 0; i < 4; ++i) {
        const int co = coBase + cog * 4 + i;
        float v[4] = {0.0f, 0.0f, 0.0f, 0.0f};
        #pragma unroll
        for (int t = 0; t < 4; ++t) {
            const int tb = t * B_SZ + b;
            const size_t off = ((size_t)tb * CO + co) * N_SP + nW + ng * 4;
            if constexpr (MODE == 0) {
                u32 pk = 0;
                #pragma unroll
                for (int e = 0; e < 4; ++e) {
                    const float y = acc[t][i][e] * scale[i] + shift[i];
                    v[e] += (y - v[e]) * 0.5f;
                    const u32 s = (v[e] >= 0.5f) ? 1u : 0u;
                    v[e] = s ? 0.0f : v[e];
                    pk |= s << (8 * e);
                }
                *reinterpret_cast<u32*>((u8*)Yv + off) = pk;
            } else if constexpr (MODE == 1) {
                float4 r0 = *reinterpret_cast<const float4*>(res + off);
                float rr2[4] = {r0.x, r0.y, r0.z, r0.w};
                float o[4];
                #pragma unroll
                for (int e = 0; e < 4; ++e)
                    o[e] = acc[t][i][e] * scale[i] + shift[i] + rr2[e];
                float4 s0 = {o[0], o[1], o[2], o[3]};
                *reinterpret_cast<float4*>((float*)Yv + off) = s0;
            } else {
                float* op = (float*)Yv + off;
                float4 r0 = *reinterpret_cast<const float4*>(op);
                float rr2[4] = {r0.x, r0.y, r0.z, r0.w};
                float o[4];
                #pragma unroll
                for (int e = 0; e < 4; ++e) {
                    const float y = acc[t][i][e] * scale[i] + shift[i];
                    v[e] += (y - v[e]) * 0.5f;
                    const u32 s = (v[e] >= 0.5f) ? 1u : 0u;
                    v[e] = s ? 0.0f : v[e];
                    o[e] = rr2[e] + (s ? 1.0f : 0.0f);
                }
                float4 s0 = {o[0], o[1], o[2], o[3]};
                *reinterpret_cast<float4*>(op) = s0;
            }
        }
    }
}

// ---------------------------------------------------------------------------
// kv_raw[row=tb*C+c] = sum_n k*v  (exact integer; round-2 verbatim)
// ---------------------------------------------------------------------------
__global__ __launch_bounds__(256) void kv_reduce(const u8* __restrict__ ks,
                                                 const u8* __restrict__ vs,
                                                 float* __restrict__ kv)
{
    const int row = blockIdx.x * 4 + (threadIdx.x >> 6);  // [0, T*B*C)
    const int lane = threadIdx.x & 63;
    const u8* kp = ks + (size_t)row * N_SP;
    const u8* vp = vs + (size_t)row * N_SP;
    int acc = 0;
    #pragma unroll
    for (int n = 0; n < N_SP; n += 256) {
        uchar4 a = *reinterpret_cast<const uchar4*>(kp + n + lane * 4);
        uchar4 c = *reinterpret_cast<const uchar4*>(vp + n + lane * 4);
        acc += (a.x & c.x) + (a.y & c.y) + (a.z & c.z) + (a.w & c.w);
    }
    #pragma unroll
    for (int off = 32; off; off >>= 1) acc += __shfl_down(acc, off, 64);
    if (lane == 0) kv[row] = (float)acc;
}

// ---------------------------------------------------------------------------
// talking heads (8x8 over heads) + LIF -> kvs float {0,1}  (round-2 verbatim)
// ---------------------------------------------------------------------------
__global__ __launch_bounds__(256) void th_lif(const float* __restrict__ kvraw,
                                              const float* __restrict__ th,
                                              float* __restrict__ kvs)
{
    const int i = blockIdx.x * 256 + threadIdx.x;   // [0, B*C)
    const int b = i >> 9;
    const int c = i & 511;
    const int g = c >> 6;
    const int dd = c & 63;
    float v = 0.0f;
    #pragma unroll
    for (int t = 0; t < T_STEPS; ++t) {
        const float* base = kvraw + ((size_t)t * B_SZ + b) * C_IN;
        float x = 0.0f;
        #pragma unroll
        for (int hh = 0; hh < 8; ++hh)
            x += base[hh * 64 + dd] * th[g * 8 + hh];
        v += (x - v) * 0.5f;
        const float s = (v >= 0.5f) ? 1.0f : 0.0f;
        kvs[((size_t)t * B_SZ + b) * C_IN + c] = s;
        v = (s != 0.0f) ? 0.0f : v;
    }
}

extern "C" void kernel_launch(void* const* d_in, const int* in_sizes, int n_in,
                              void* d_out, int out_size, void* d_ws, size_t ws_size,
                              hipStream_t stream)
{
    const float* x       = (const float*)d_in[0];
    const float* q_w     = (const float*)d_in[1];
    const float* q_bn    = (const float*)d_in[2];
    const float* k_w     = (const float*)d_in[3];
    const float* k_bn    = (const float*)d_in[4];
    const float* v_w     = (const float*)d_in[5];
    const float* v_bn    = (const float*)d_in[6];
    const float* th_w    = (const float*)d_in[7];
    const float* proj_w  = (const float*)d_in[8];
    const float* proj_b  = (const float*)d_in[9];
    const float* proj_bn = (const float*)d_in[10];
    const float* fc1_w   = (const float*)d_in[11];
    const float* fc1_b   = (const float*)d_in[12];
    const float* fc1_bn  = (const float*)d_in[13];
    const float* fc2_w   = (const float*)d_in[14];
    const float* fc2_b   = (const float*)d_in[15];
    const float* fc2_bn  = (const float*)d_in[16];
    float* out = (float*)d_out;

    // workspace: round-2/6/9/13's proven 64 MiB + 128 KiB map
    u8* ws = (u8*)d_ws;
    const size_t SLOT = (size_t)T_STEPS * S_C;        // 16 MiB per u8 slot
    u8* xs = ws;                    // [TB][C][N] u8
    u8* qs = ws + SLOT;
    u8* ks = ws + 2 * SLOT;
    u8* vs = ws + 3 * SLOT;
    float* kvraw = (float*)(ws + 4 * SLOT);                 // [TB][C] f32 (64 KiB)
    float* kvsf  = kvraw + (size_t)T_STEPS * B_SZ * C_IN;   // [TB][C] f32 (64 KiB)
    u8* hdn = ws;                   // [TB][Ch][N] u8 = 64 MiB, reuses xs..vs (dead by fc1)

    // 1. xs = lif(x)
    lif_x_kernel<<<(int)(S_C / 256), 256, 0, stream>>>(x, xs);

    // 2. q/k/v = lif(bn(conv(xs)))  — fused triple GEMM, t-folded, barrier-free
    //    grid = 16 nblk * 8 cb * 3 sel * 8 b = 3072
    mm<0, 0, false, 512, 512, 3><<<3072, 256, 0, stream>>>(
        q_w, k_w, v_w, xs, q_bn, k_bn, v_bn, nullptr, nullptr, nullptr, qs, ks, vs);

    // 3. kv_raw = rowwise dot(k, v); 4. talking heads + lif -> kvs (float 0/1)
    kv_reduce<<<(T_STEPS * B_SZ * C_IN) / 4, 256, 0, stream>>>(ks, vs, kvraw);
    th_lif<<<(B_SZ * C_IN) / 256, 256, 0, stream>>>(kvraw, th_w, kvsf);

    // 5. xout = bn(proj(q * kvs) + b) + x  -> d_out;  grid 16*8*8 = 1024
    mm<1, 1, true, 512, 512, 1><<<1024, 256, 0, stream>>>(
        proj_w, nullptr, nullptr, qs, proj_bn, nullptr, nullptr, proj_b, kvsf, x,
        out, nullptr, nullptr);

    // 6. hdn = lif(bn(fc1(xout) + b));  grid 16*32*8 = 4096
    mm<0, 2, true, 512, 2048, 1><<<4096, 256, 0, stream>>>(
        fc1_w, nullptr, nullptr, out, fc1_bn, nullptr, nullptr, fc1_b, nullptr, nullptr,
        hdn, nullptr, nullptr);

    // 7. out = lif(bn(fc2(hdn) + b)) + xout  (in place on d_out);  grid 1024
    mm<2, 0, true, 2048, 512, 1><<<1024, 256, 0, stream>>>(
        fc2_w, nullptr, nullptr, hdn, fc2_bn, nullptr, nullptr, fc2_b, nullptr, nullptr,
        out, nullptr, nullptr);
}